// Round 10
// baseline (390.933 us; speedup 1.0000x reference)
//
#include <hip/hip_runtime.h>
#include <stdint.h>
#include <math.h>

typedef __bf16 bf16x8 __attribute__((ext_vector_type(8)));
typedef float f32x4 __attribute__((ext_vector_type(4)));
typedef unsigned short u16x8 __attribute__((ext_vector_type(8)));

__device__ __forceinline__ unsigned short f32_to_bf16_rne(float f) {
    unsigned u = __builtin_bit_cast(unsigned, f);
    u += 0x7fffu + ((u >> 16) & 1u);
    return (unsigned short)(u >> 16);
}

// ---------------------------------------------------------------------------
// int8 symmetric group-wise fake-quant, group 128 along contiguous axis.
// 32 lanes per group, one float4 per lane. Output = bf16(q*scale).
// At HBM BW roofline — unchanged.
// ---------------------------------------------------------------------------
__global__ __launch_bounds__(256) void quant_fake_int8_kernel(
    const float* __restrict__ in, unsigned short* __restrict__ out,
    long long n) {
    long long t = (long long)blockIdx.x * 256 + threadIdx.x;
    long long base = t * 4;
    if (base >= n) return;
    const float4 v = *reinterpret_cast<const float4*>(in + base);
    float m = fmaxf(fmaxf(fabsf(v.x), fabsf(v.y)),
                    fmaxf(fabsf(v.z), fabsf(v.w)));
#pragma unroll
    for (int off = 1; off <= 16; off <<= 1)
        m = fmaxf(m, __shfl_xor(m, off, 64));
    const float scale = fmaxf(m / 127.0f, 1e-8f);
    const float d0 = fminf(fmaxf(rintf(v.x / scale), -128.0f), 127.0f) * scale;
    const float d1 = fminf(fmaxf(rintf(v.y / scale), -128.0f), 127.0f) * scale;
    const float d2 = fminf(fmaxf(rintf(v.z / scale), -128.0f), 127.0f) * scale;
    const float d3 = fminf(fmaxf(rintf(v.w / scale), -128.0f), 127.0f) * scale;
    ushort4 o;
    o.x = f32_to_bf16_rne(d0);
    o.y = f32_to_bf16_rne(d1);
    o.z = f32_to_bf16_rne(d2);
    o.w = f32_to_bf16_rne(d3);
    *reinterpret_cast<ushort4*>(out + base) = o;
}

// ---------------------------------------------------------------------------
// REGISTER-STREAMING bf16 GEMM — no LDS, no barriers, no explicit waitcnt.
// C[M][N] = A[M][K] * B[N][K]^T. 512 thr = 8 waves (2M x 4N), wave 128x64.
//
// Each wave loads its own MFMA fragments straight from global into VGPRs:
// frag (m, step s) = 16 rows x 32 k of A; lane(l15,lh) reads 8 contiguous
// bf16 at (rowA + m*16)*K + s*32 + lh*8 — a global_load_dwordx4 touching 16
// full 64B lines (4 lanes/line), the same pattern ds_read_b128 had in LDS.
// K-step 32: per step per wave A = 8 frags, B = 4 frags (12 loads, 48
// VGPRs), double register sets (sets consumed at step s are reloaded for
// s+2 AFTER the step-s MFMAs issue -> no WAR, ~1.5-step latency cover).
// Compiler inserts its own counted vmcnt before each first use (m97
// evidence) — waves are fully self-paced; the matrix pipe never waits on
// a block-wide barrier or an LDS drain.
// Duplication (A frags read by 4 waves, B by 2) is served by L1 (per-step
// unique window A+B = 32 KB) and by the per-XCD L2 (panels shared by 8 CUs
// via the XCD-chunked remap).
// ---------------------------------------------------------------------------
#define BM 256
#define BN 256

#define LDG(P) __builtin_bit_cast(bf16x8, *reinterpret_cast<const u16x8*>(P))
#define MFMA(a, bb, c) __builtin_amdgcn_mfma_f32_16x16x32_bf16(a, bb, c, 0, 0, 0)

__global__ __launch_bounds__(512, 2) void gemm_bf16_reg(
    const unsigned short* __restrict__ A,  // [M][K] bf16 bits
    const unsigned short* __restrict__ B,  // [N][K] bf16 bits
    float* __restrict__ C,                 // [M][N]
    int M, int N, int K) {
    const int tid = threadIdx.x;
    const int lane = tid & 63;
    const int wid = tid >> 6;
    const int wr = wid >> 2;  // 0..1  (M half)
    const int wc = wid & 3;   // 0..3  (N quarter)
    const int l15 = lane & 15;
    const int lh = lane >> 4;

    // XCD-chunked bijective remap over 512 blocks (512 % 8 == 0).
    const int id = (blockIdx.x & 7) * 64 + (blockIdx.x >> 3);
    const int tileN = (id & 7) * BN;
    const int tileM = (id >> 3) * BM;

    // per-lane fragment base pointers (frag m at + m*16*K, step s at + s*32)
    const unsigned short* pA =
        A + (size_t)(tileM + wr * 128 + l15) * K + lh * 8;
    const unsigned short* pB =
        B + (size_t)(tileN + wc * 64 + l15) * K + lh * 8;
    const size_t FS = (size_t)16 * K;  // frag row-block stride (elems)

    const int NS = K >> 5;  // 64 K-steps of 32

    f32x4 acc[8][4] = {};
    bf16x8 a0[8], a1[8], b0[4], b1[4];

    // ---- prologue: load steps 0 and 1 into both register sets ----
#pragma unroll
    for (int m = 0; m < 8; ++m) a0[m] = LDG(pA + (size_t)m * FS);
#pragma unroll
    for (int n = 0; n < 4; ++n) b0[n] = LDG(pB + (size_t)n * FS);
#pragma unroll
    for (int m = 0; m < 8; ++m) a1[m] = LDG(pA + (size_t)m * FS + 32);
#pragma unroll
    for (int n = 0; n < 4; ++n) b1[n] = LDG(pB + (size_t)n * FS + 32);

#pragma unroll 1
    for (int s = 0; s < NS; s += 2) {
        // ---------- body 0: consume set0 (step s), reload set0 (s+2) ------
#pragma unroll
        for (int n = 0; n < 4; ++n) {
            acc[0][n] = MFMA(a0[0], b0[n], acc[0][n]);
            acc[1][n] = MFMA(a0[1], b0[n], acc[1][n]);
            acc[2][n] = MFMA(a0[2], b0[n], acc[2][n]);
            acc[3][n] = MFMA(a0[3], b0[n], acc[3][n]);
            acc[4][n] = MFMA(a0[4], b0[n], acc[4][n]);
            acc[5][n] = MFMA(a0[5], b0[n], acc[5][n]);
            acc[6][n] = MFMA(a0[6], b0[n], acc[6][n]);
            acc[7][n] = MFMA(a0[7], b0[n], acc[7][n]);
        }
        if (s + 2 < NS) {
            const int off = (s + 2) * 32;
#pragma unroll
            for (int m = 0; m < 8; ++m) a0[m] = LDG(pA + (size_t)m * FS + off);
#pragma unroll
            for (int n = 0; n < 4; ++n) b0[n] = LDG(pB + (size_t)n * FS + off);
        }
        // ---------- body 1: consume set1 (step s+1), reload set1 (s+3) ----
#pragma unroll
        for (int n = 0; n < 4; ++n) {
            acc[0][n] = MFMA(a1[0], b1[n], acc[0][n]);
            acc[1][n] = MFMA(a1[1], b1[n], acc[1][n]);
            acc[2][n] = MFMA(a1[2], b1[n], acc[2][n]);
            acc[3][n] = MFMA(a1[3], b1[n], acc[3][n]);
            acc[4][n] = MFMA(a1[4], b1[n], acc[4][n]);
            acc[5][n] = MFMA(a1[5], b1[n], acc[5][n]);
            acc[6][n] = MFMA(a1[6], b1[n], acc[6][n]);
            acc[7][n] = MFMA(a1[7], b1[n], acc[7][n]);
        }
        if (s + 3 < NS) {
            const int off = (s + 3) * 32;
#pragma unroll
            for (int m = 0; m < 8; ++m) a1[m] = LDG(pA + (size_t)m * FS + off);
#pragma unroll
            for (int n = 0; n < 4; ++n) b1[n] = LDG(pB + (size_t)n * FS + off);
        }
    }

    // ---- epilogue: C/D layout col = lane&15, row = (lane>>4)*4 + reg ----
    const int c0 = tileN + wc * 64 + l15;
    const int r0 = tileM + wr * 128 + lh * 4;
#pragma unroll
    for (int m = 0; m < 8; ++m)
#pragma unroll
        for (int n = 0; n < 4; ++n)
#pragma unroll
            for (int r = 0; r < 4; ++r)
                C[(size_t)(r0 + m * 16 + r) * N + (c0 + n * 16)] =
                    acc[m][n][r];
}

// ---------------------------------------------------------------------------
extern "C" void kernel_launch(void* const* d_in, const int* in_sizes, int n_in,
                              void* d_out, int out_size, void* d_ws,
                              size_t ws_size, hipStream_t stream) {
    const float* x = (const float*)d_in[0];  // [B,S,IN]  f32
    const float* w = (const float*)d_in[1];  // [OUT,IN]  f32
    float* out = (float*)d_out;              // [B,S,OUT] f32

    const long long MK = (long long)in_sizes[0];
    const long long NK = (long long)in_sizes[1];
    const long long MN = (long long)out_size;
    const long long K =
        (long long)(sqrt((double)MK * (double)NK / (double)MN) + 0.5);
    const long long M = MK / K;  // 16384
    const long long N = NK / K;  // 2048

    unsigned short* qx = (unsigned short*)d_ws;  // M*K bf16
    unsigned short* qw = qx + MK;                // N*K bf16

    quant_fake_int8_kernel<<<(int)(MK / 1024), 256, 0, stream>>>(x, qx, MK);
    quant_fake_int8_kernel<<<(int)(NK / 1024), 256, 0, stream>>>(w, qw, NK);

    dim3 grid((int)((M / BM) * (N / BN)));  // 64 * 8 = 512
    gemm_bf16_reg<<<grid, 512, 0, stream>>>(qx, qw, out, (int)M, (int)N,
                                            (int)K);
}

// Round 11
// 226.649 us; speedup vs baseline: 1.7248x; 1.7248x over previous
//
#include <hip/hip_runtime.h>
#include <stdint.h>
#include <math.h>

typedef __bf16 bf16x8 __attribute__((ext_vector_type(8)));
typedef float f32x4 __attribute__((ext_vector_type(4)));
typedef unsigned short u16x8 __attribute__((ext_vector_type(8)));

__device__ __forceinline__ unsigned short f32_to_bf16_rne(float f) {
    unsigned u = __builtin_bit_cast(unsigned, f);
    u += 0x7fffu + ((u >> 16) & 1u);
    return (unsigned short)(u >> 16);
}

// ---------------------------------------------------------------------------
// int8 symmetric group-wise fake-quant, group 128 along contiguous axis.
// 32 lanes per group, one float4 per lane. Output = bf16(q*scale).
// At HBM BW roofline — unchanged.
// ---------------------------------------------------------------------------
__global__ __launch_bounds__(256) void quant_fake_int8_kernel(
    const float* __restrict__ in, unsigned short* __restrict__ out,
    long long n) {
    long long t = (long long)blockIdx.x * 256 + threadIdx.x;
    long long base = t * 4;
    if (base >= n) return;
    const float4 v = *reinterpret_cast<const float4*>(in + base);
    float m = fmaxf(fmaxf(fabsf(v.x), fabsf(v.y)),
                    fmaxf(fabsf(v.z), fabsf(v.w)));
#pragma unroll
    for (int off = 1; off <= 16; off <<= 1)
        m = fmaxf(m, __shfl_xor(m, off, 64));
    const float scale = fmaxf(m / 127.0f, 1e-8f);
    const float d0 = fminf(fmaxf(rintf(v.x / scale), -128.0f), 127.0f) * scale;
    const float d1 = fminf(fmaxf(rintf(v.y / scale), -128.0f), 127.0f) * scale;
    const float d2 = fminf(fmaxf(rintf(v.z / scale), -128.0f), 127.0f) * scale;
    const float d3 = fminf(fmaxf(rintf(v.w / scale), -128.0f), 127.0f) * scale;
    ushort4 o;
    o.x = f32_to_bf16_rne(d0);
    o.y = f32_to_bf16_rne(d1);
    o.z = f32_to_bf16_rne(d2);
    o.w = f32_to_bf16_rne(d3);
    *reinterpret_cast<ushort4*>(out + base) = o;
}

// ---------------------------------------------------------------------------
// HYBRID bf16 GEMM: A via swizzled ring-3 LDS (round-9 structure), B via
// global->register prefetch (1 K-tile ahead, double register set).
// C[M][N] = A[M][K] * B[N][K]^T. 512 thr = 8 waves (2M x 4N), wave 128x64.
//
// Why: rounds 2-9 all measured ~4930 cyc per K-tile-64/CU = MFMA(2483) +
// LDS fabric(2450) SERIALIZED. Removing B from LDS cuts fabric to ~1760 cyc
// (A frag reads 128 KB + A stage writes 32 KB) < MFMA -> matrix pipe
// becomes critical. B frag loads (16 B/lane, 16 full 64B lines per instr)
// hit L1/L2: per-CU B traffic 64 KB/K-tile ~= 31 B/cyc.
//
// vmcnt ledger (in-order per-wave queue; B-frag loads and A-stage loads
// both count):
//   steady state at tile-kt top (after prev boundary): [B(kt) 8][A(kt+1) 4]
//     -> vmcnt(4) readies all B(kt) fragments.
//   body kt issues: B(kt+1) [8], then A-stage(kt+2) [4] -> 16 outstanding.
//   boundary: vmcnt(12) drains A(kt+1) exactly (for next tile's ds_reads);
//     leaves [B(kt+1) 8][A(kt+2) 4] = steady state. Tails: kt=NT-2 ->
//     vmcnt(8) (no A-stage issued); kt=NT-1 -> none.
//   Prologue order matters: stage A0 [4], load B0 [8], stage A1 [4];
//     vmcnt(12) drains A0, leaves [B0 8][A1 4] = steady shape.
// WAR on A ring (1 barrier/tile): stage(kt+2) writes slot (kt-1)%3; every
// wave's ds_reads of that slot were consumed by its MFMAs before it reached
// barrier kt -> safe (round-9-verified pattern).
// B double-set registers are statically named (bA/bB, unrolled parity) to
// avoid scratch (rule: no runtime-indexed ext_vector arrays).
// Swizzle (128B rows): colbyte ^ ((row&7)<<4), pre-swizzled global source +
// swizzled read address. Verified 0 conflicts (rounds 2,8,9).
// ---------------------------------------------------------------------------
#define BM 256
#define BN 256
#define NSLOT 16384  // elems per 32 KB A-slot ([256][64] bf16)

__device__ __forceinline__ void gload16(const unsigned short* g,
                                        unsigned short* l) {
    __builtin_amdgcn_global_load_lds(
        (const __attribute__((address_space(1))) void*)(g),
        (__attribute__((address_space(3))) void*)(l), 16, 0, 0);
}

// Stage a full [256][64] A-tile: 4 gload_lds x 512 thr x 16 B = 32 KB.
__device__ __forceinline__ void stageA(const unsigned short* __restrict__ G,
                                       unsigned short* L, int tid, int baseRow,
                                       int K, int k0) {
    const int srow = tid >> 3;                                   // 0..63
    const int scb = (((tid & 7) << 4) ^ ((srow & 7) << 4)) >> 1; // elem col
#pragma unroll
    for (int i = 0; i < 4; ++i)
        gload16(G + (size_t)(baseRow + i * 64 + srow) * K + k0 + scb,
                L + i * 4096 + (tid >> 6) * 512);
}

#define LDF(BASE, ROW, COE)                                      \
    __builtin_bit_cast(bf16x8, *reinterpret_cast<const u16x8*>(  \
                                   (BASE) + (((ROW) << 6) + (COE))))
#define LDG(P) __builtin_bit_cast(bf16x8, *reinterpret_cast<const u16x8*>(P))
#define MFMA(a, bb, c) __builtin_amdgcn_mfma_f32_16x16x32_bf16(a, bb, c, 0, 0, 0)

__global__ __launch_bounds__(512, 2) void gemm_bf16_hyb(
    const unsigned short* __restrict__ A,  // [M][K] bf16 bits
    const unsigned short* __restrict__ B,  // [N][K] bf16 bits
    float* __restrict__ C,                 // [M][N]
    int M, int N, int K) {
    __shared__ __align__(16) unsigned short smem[3 * NSLOT];  // 96 KB

    const int tid = threadIdx.x;
    const int lane = tid & 63;
    const int wid = tid >> 6;
    const int wr = wid >> 2;  // 0..1  (M half)
    const int wc = wid & 3;   // 0..3  (N quarter)
    const int l15 = lane & 15;
    const int lh = lane >> 4;
    const int swz = (lane & 7) << 4;
    const int coe0 = ((lh << 4) ^ swz) >> 1;        // kk=0 elem col
    const int coe1 = (((lh << 4) | 64) ^ swz) >> 1; // kk=1 elem col
    const int ra = wr * 128 + l15;                  // + m*16

    // XCD-chunked bijective remap over 512 blocks (512 % 8 == 0).
    const int id = (blockIdx.x & 7) * 64 + (blockIdx.x >> 3);
    const int tileN = (id & 7) * BN;
    const int tileM = (id >> 3) * BM;

    // B fragment base: row (tileN + wc*64 + n*16 + l15), 16 B at k + lh*8.
    const unsigned short* pB =
        B + (size_t)(tileN + wc * 64 + l15) * K + lh * 8;
    const size_t BFS = (size_t)16 * K;  // per-n row-block stride (elems)

    const int NT = K >> 6;  // 32

    f32x4 acc[8][4] = {};
    bf16x8 bA[8], bB[8];  // B frag sets: [2n+kk]; parity-swapped per tile

    unsigned short* pa0 = smem + 0 * NSLOT;  // A(kt)
    unsigned short* pa1 = smem + 1 * NSLOT;  // A(kt+1)
    unsigned short* pa2 = smem + 2 * NSLOT;  // A(kt+2) staging target

    // ---- prologue: A0 [4], B0 [8], A1 [4]; drain A0 (vmcnt 12) ----
    stageA(A, pa0, tid, tileM, K, 0);
#pragma unroll
    for (int n = 0; n < 4; ++n) {
        bA[2 * n] = LDG(pB + n * BFS);
        bA[2 * n + 1] = LDG(pB + n * BFS + 32);
    }
    stageA(A, pa1, tid, tileM, K, 64);
    asm volatile("s_waitcnt vmcnt(12)" ::: "memory");
    __builtin_amdgcn_s_barrier();

#define GBODY(KT, CUR, NXT)                                                   \
    {                                                                         \
        const int kt = (KT);                                                  \
        /* ready all B(kt) fragments (also drained by compiler's dep wait) */ \
        if (kt == NT - 1)                                                     \
            asm volatile("s_waitcnt vmcnt(0)" ::: "memory");                  \
        else                                                                  \
            asm volatile("s_waitcnt vmcnt(4)" ::: "memory");                  \
        if (kt + 1 < NT) {                                                    \
            const int off1 = (kt + 1) << 6;                                   \
            _Pragma("unroll") for (int n = 0; n < 4; ++n) {                   \
                NXT[2 * n] = LDG(pB + n * BFS + off1);                        \
                NXT[2 * n + 1] = LDG(pB + n * BFS + off1 + 32);               \
            }                                                                 \
        }                                                                     \
        if (kt + 2 < NT) stageA(A, pa2, tid, tileM, K, (kt + 2) << 6);        \
        const unsigned short* Ab = pa0;                                       \
        {                                                                     \
            bf16x8 a00 = LDF(Ab, ra + 0, coe0), a01 = LDF(Ab, ra + 0, coe1);  \
            bf16x8 a10 = LDF(Ab, ra + 16, coe0), a11 = LDF(Ab, ra + 16, coe1);\
            bf16x8 a20 = LDF(Ab, ra + 32, coe0), a21 = LDF(Ab, ra + 32, coe1);\
            bf16x8 a30 = LDF(Ab, ra + 48, coe0), a31 = LDF(Ab, ra + 48, coe1);\
            __builtin_amdgcn_s_setprio(1);                                    \
            _Pragma("unroll") for (int n = 0; n < 4; ++n) {                   \
                acc[0][n] = MFMA(a01, CUR[2 * n + 1],                         \
                                 MFMA(a00, CUR[2 * n], acc[0][n]));           \
                acc[1][n] = MFMA(a11, CUR[2 * n + 1],                         \
                                 MFMA(a10, CUR[2 * n], acc[1][n]));           \
                acc[2][n] = MFMA(a21, CUR[2 * n + 1],                         \
                                 MFMA(a20, CUR[2 * n], acc[2][n]));           \
                acc[3][n] = MFMA(a31, CUR[2 * n + 1],                         \
                                 MFMA(a30, CUR[2 * n], acc[3][n]));           \
            }                                                                 \
            __builtin_amdgcn_s_setprio(0);                                    \
        }                                                                     \
        {                                                                     \
            bf16x8 a00 = LDF(Ab, ra + 64, coe0), a01 = LDF(Ab, ra + 64, coe1);\
            bf16x8 a10 = LDF(Ab, ra + 80, coe0), a11 = LDF(Ab, ra + 80, coe1);\
            bf16x8 a20 = LDF(Ab, ra + 96, coe0), a21 = LDF(Ab, ra + 96, coe1);\
            bf16x8 a30 = LDF(Ab, ra + 112, coe0),                             \
                   a31 = LDF(Ab, ra + 112, coe1);                             \
            __builtin_amdgcn_s_setprio(1);                                    \
            _Pragma("unroll") for (int n = 0; n < 4; ++n) {                   \
                acc[4][n] = MFMA(a01, CUR[2 * n + 1],                         \
                                 MFMA(a00, CUR[2 * n], acc[4][n]));           \
                acc[5][n] = MFMA(a11, CUR[2 * n + 1],                         \
                                 MFMA(a10, CUR[2 * n], acc[5][n]));           \
                acc[6][n] = MFMA(a21, CUR[2 * n + 1],                         \
                                 MFMA(a20, CUR[2 * n], acc[6][n]));           \
                acc[7][n] = MFMA(a31, CUR[2 * n + 1],                         \
                                 MFMA(a30, CUR[2 * n], acc[7][n]));           \
            }                                                                 \
            __builtin_amdgcn_s_setprio(0);                                    \
        }                                                                     \
        if (kt + 2 < NT)                                                      \
            asm volatile("s_waitcnt vmcnt(12)" ::: "memory");                 \
        else if (kt + 1 < NT)                                                 \
            asm volatile("s_waitcnt vmcnt(8)" ::: "memory");                  \
        if (kt + 1 < NT) __builtin_amdgcn_s_barrier();                        \
        unsigned short* t = pa0;                                              \
        pa0 = pa1;                                                            \
        pa1 = pa2;                                                            \
        pa2 = t;                                                              \
    }

#pragma unroll 1
    for (int kt2 = 0; kt2 < NT; kt2 += 2) {
        GBODY(kt2, bA, bB)
        GBODY(kt2 + 1, bB, bA)
    }

    // ---- epilogue: C/D layout col = lane&15, row = (lane>>4)*4 + reg ----
    const int c0 = tileN + wc * 64 + l15;
    const int r0 = tileM + wr * 128 + lh * 4;
#pragma unroll
    for (int m = 0; m < 8; ++m)
#pragma unroll
        for (int n = 0; n < 4; ++n)
#pragma unroll
            for (int r = 0; r < 4; ++r)
                C[(size_t)(r0 + m * 16 + r) * N + (c0 + n * 16)] =
                    acc[m][n][r];
}

// ---------------------------------------------------------------------------
extern "C" void kernel_launch(void* const* d_in, const int* in_sizes, int n_in,
                              void* d_out, int out_size, void* d_ws,
                              size_t ws_size, hipStream_t stream) {
    const float* x = (const float*)d_in[0];  // [B,S,IN]  f32
    const float* w = (const float*)d_in[1];  // [OUT,IN]  f32
    float* out = (float*)d_out;              // [B,S,OUT] f32

    const long long MK = (long long)in_sizes[0];
    const long long NK = (long long)in_sizes[1];
    const long long MN = (long long)out_size;
    const long long K =
        (long long)(sqrt((double)MK * (double)NK / (double)MN) + 0.5);
    const long long M = MK / K;  // 16384
    const long long N = NK / K;  // 2048

    unsigned short* qx = (unsigned short*)d_ws;  // M*K bf16
    unsigned short* qw = qx + MK;                // N*K bf16

    quant_fake_int8_kernel<<<(int)(MK / 1024), 256, 0, stream>>>(x, qx, MK);
    quant_fake_int8_kernel<<<(int)(NK / 1024), 256, 0, stream>>>(w, qw, NK);

    dim3 grid((int)((M / BM) * (N / BN)));  // 64 * 8 = 512
    gemm_bf16_hyb<<<grid, 512, 0, stream>>>(qx, qw, out, (int)M, (int)N,
                                            (int)K);
}

// Round 12
// 174.486 us; speedup vs baseline: 2.2405x; 1.2990x over previous
//
#include <hip/hip_runtime.h>
#include <stdint.h>
#include <math.h>

typedef __bf16 bf16x8 __attribute__((ext_vector_type(8)));
typedef float f32x4 __attribute__((ext_vector_type(4)));
typedef unsigned short u16x8 __attribute__((ext_vector_type(8)));

__device__ __forceinline__ unsigned short f32_to_bf16_rne(float f) {
    unsigned u = __builtin_bit_cast(unsigned, f);
    u += 0x7fffu + ((u >> 16) & 1u);
    return (unsigned short)(u >> 16);
}

// ---------------------------------------------------------------------------
// int8 symmetric group-wise fake-quant, group 128 along contiguous axis.
// 32 lanes per group, one float4 per lane. Output = bf16(q*scale).
// At HBM BW roofline — unchanged.
// ---------------------------------------------------------------------------
__global__ __launch_bounds__(256) void quant_fake_int8_kernel(
    const float* __restrict__ in, unsigned short* __restrict__ out,
    long long n) {
    long long t = (long long)blockIdx.x * 256 + threadIdx.x;
    long long base = t * 4;
    if (base >= n) return;
    const float4 v = *reinterpret_cast<const float4*>(in + base);
    float m = fmaxf(fmaxf(fabsf(v.x), fabsf(v.y)),
                    fmaxf(fabsf(v.z), fabsf(v.w)));
#pragma unroll
    for (int off = 1; off <= 16; off <<= 1)
        m = fmaxf(m, __shfl_xor(m, off, 64));
    const float scale = fmaxf(m / 127.0f, 1e-8f);
    const float d0 = fminf(fmaxf(rintf(v.x / scale), -128.0f), 127.0f) * scale;
    const float d1 = fminf(fmaxf(rintf(v.y / scale), -128.0f), 127.0f) * scale;
    const float d2 = fminf(fmaxf(rintf(v.z / scale), -128.0f), 127.0f) * scale;
    const float d3 = fminf(fmaxf(rintf(v.w / scale), -128.0f), 127.0f) * scale;
    ushort4 o;
    o.x = f32_to_bf16_rne(d0);
    o.y = f32_to_bf16_rne(d1);
    o.z = f32_to_bf16_rne(d2);
    o.w = f32_to_bf16_rne(d3);
    *reinterpret_cast<ushort4*>(out + base) = o;
}

// ---------------------------------------------------------------------------
// 256x256 bf16 GEMM — faithful 8-phase template (m201 structure).
// C[M][N] = A[M][K] * B[N][K]^T. 512 thr = 8 waves (2M x 4N), wave 128x64.
// BK=64; LDS = 2 dbuf x (A 32K + B 32K) = 128 KB; tile kt lives in buf kt&1.
// Iter = 2 K-tiles (t even): phases 1-4 compute tile t (buf0), 5-8 tile t+1
// (buf1). Phase = {ds_reads; stage 1 half-tile (2 gloads); [lgkmcnt(8) if
// 12 reads]; [vmcnt(4) at p4/p8]; s_barrier; lgkmcnt(0); setprio(1);
// 16 MFMA (one C-quadrant x K=64); setprio(0); s_barrier}.
// Quadrant reads: p1/p5 = A m0-3 x2kk [8] + B n0-1 x2kk [4] (12);
// p2/p6 = B n2-3 x2kk [4]; p3/p7 = A m4-7 x2kk [8]; p4/p8 = 0.
//
// Stage schedule (2 gloads/phase; each region staged >=1 tail-barrier after
// its last reader):
//   p1: A(t+1)h0 -> buf1   (buf1 A last read prev-iter p7)
//   p2: A(t+1)h1 -> buf1
//   p3: B(t+2)h0 -> buf0   (buf0 B last read this-iter p2)
//   p4: B(t+2)h1 -> buf0
//   p5: A(t+2)h0 -> buf0   (buf0 A last read this-iter p3)
//   p6: A(t+2)h1 -> buf0
//   p7: B(t+3)h0 -> buf1   (buf1 B last read this-iter p6)
//   p8: B(t+3)h1 -> buf1
// vmcnt ledger (in-order, 2 loads/stage):
//   entering p1 (steady): in flight = [B(t+1) 4] (prev p7,p8).
//   p4: outstanding = B(t+1)4 + A(t+1)4 + B(t+2)4 = 12 -> vmcnt(4) drains
//       B(t+1)+A(t+1) (both needed at p5), leaves B(t+2).
//   p8: outstanding = B(t+2)4 + A(t+2)4 + B(t+3)4 = 12 -> vmcnt(4) drains
//       B(t+2)+A(t+2) (needed next p1), leaves B(t+3) = steady state.
//   Prologue: stage A(0),B(0),B(1); vmcnt(4) leaves B(1) in flight.
//   Tail (t = NT-2): p3/p4/p5-p8 stages skipped; p4 -> vmcnt(0); p8 none.
// Swizzle (128B rows): colbyte ^ ((row&7)<<4), pre-swizzled global source +
// swizzled read address (both-sides). Measured 0 conflicts (rounds 2,8,9).
// ---------------------------------------------------------------------------
#define BM 256
#define BN 256
#define NSLOT 16384  // elems per 32 KB slot ([256][64] bf16)

__device__ __forceinline__ void gload16(const unsigned short* g,
                                        unsigned short* l) {
    __builtin_amdgcn_global_load_lds(
        (const __attribute__((address_space(1))) void*)(g),
        (__attribute__((address_space(3))) void*)(l), 16, 0, 0);
}

// Stage one half (rows h*128 .. h*128+127) of a [256][64] tile: 2 gloads.
__device__ __forceinline__ void stage_half(const unsigned short* __restrict__ G,
                                           unsigned short* L, int tid,
                                           int baseRow, int K, int k0, int h) {
    const int srow = tid >> 3;                                   // 0..63
    const int scb = (((tid & 7) << 4) ^ ((srow & 7) << 4)) >> 1; // elem col
#pragma unroll
    for (int i = 2 * h; i < 2 * h + 2; ++i)
        gload16(G + (size_t)(baseRow + i * 64 + srow) * K + k0 + scb,
                L + i * 4096 + (tid >> 6) * 512);
}

#define LDF(BASE, ROW, COE)                                      \
    __builtin_bit_cast(bf16x8, *reinterpret_cast<const u16x8*>(  \
                                   (BASE) + (((ROW) << 6) + (COE))))
#define MFMA(a, bb, c) __builtin_amdgcn_mfma_f32_16x16x32_bf16(a, bb, c, 0, 0, 0)

__global__ __launch_bounds__(512, 2) void gemm_bf16_tmpl(
    const unsigned short* __restrict__ A,  // [M][K] bf16 bits
    const unsigned short* __restrict__ B,  // [N][K] bf16 bits
    float* __restrict__ C,                 // [M][N]
    int M, int N, int K) {
    __shared__ __align__(16) unsigned short smem[2][2][NSLOT];  // 128 KB

    const int tid = threadIdx.x;
    const int lane = tid & 63;
    const int wid = tid >> 6;
    const int wr = wid >> 2;  // 0..1  (M half)
    const int wc = wid & 3;   // 0..3  (N quarter)
    const int l15 = lane & 15;
    const int lh = lane >> 4;
    const int swz = (lane & 7) << 4;
    const int coe0 = ((lh << 4) ^ swz) >> 1;        // kk=0 elem col
    const int coe1 = (((lh << 4) | 64) ^ swz) >> 1; // kk=1 elem col
    const int ra = wr * 128 + l15;                  // + m*16
    const int rb = wc * 64 + l15;                   // + n*16

    // XCD-chunked bijective remap over 512 blocks (512 % 8 == 0).
    const int id = (blockIdx.x & 7) * 64 + (blockIdx.x >> 3);
    const int tileN = (id & 7) * BN;
    const int tileM = (id >> 3) * BM;

    const int NT = K >> 6;  // 32 (even)

    f32x4 acc[8][4] = {};

    // ---- prologue: A(0), B(0), B(1); vmcnt(4) leaves B(1) in flight ----
    stage_half(A, &smem[0][0][0], tid, tileM, K, 0, 0);
    stage_half(A, &smem[0][0][0], tid, tileM, K, 0, 1);
    stage_half(B, &smem[0][1][0], tid, tileN, K, 0, 0);
    stage_half(B, &smem[0][1][0], tid, tileN, K, 0, 1);
    stage_half(B, &smem[1][1][0], tid, tileN, K, 64, 0);
    stage_half(B, &smem[1][1][0], tid, tileN, K, 64, 1);
    asm volatile("s_waitcnt vmcnt(4)" ::: "memory");
    __builtin_amdgcn_s_barrier();

#pragma unroll 1
    for (int t = 0; t < NT; t += 2) {
        const bool pf2 = (t + 2 < NT);
        const int k1 = (t + 1) << 6, k2 = (t + 2) << 6, k3 = (t + 3) << 6;

        // ================== K-tile t (buf0) ==================
        const unsigned short* Ab = &smem[0][0][0];
        const unsigned short* Bb = &smem[0][1][0];
        bf16x8 a00, a01, a10, a11, a20, a21, a30, a31;  // A m0-3 x2kk
        bf16x8 b00, b01, b10, b11;                      // B n0-1 x2kk
        bf16x8 b20, b21, b30, b31;                      // B n2-3 x2kk
        bf16x8 c00, c01, c10, c11, c20, c21, c30, c31;  // A m4-7 x2kk

        // ---- p1: Q(m0-3, n0-1), 12 reads, stage A(t+1)h0 ----
        a00 = LDF(Ab, ra + 0, coe0);  a01 = LDF(Ab, ra + 0, coe1);
        a10 = LDF(Ab, ra + 16, coe0); a11 = LDF(Ab, ra + 16, coe1);
        a20 = LDF(Ab, ra + 32, coe0); a21 = LDF(Ab, ra + 32, coe1);
        a30 = LDF(Ab, ra + 48, coe0); a31 = LDF(Ab, ra + 48, coe1);
        b00 = LDF(Bb, rb + 0, coe0);  b01 = LDF(Bb, rb + 0, coe1);
        b10 = LDF(Bb, rb + 16, coe0); b11 = LDF(Bb, rb + 16, coe1);
        stage_half(A, &smem[1][0][0], tid, tileM, K, k1, 0);
        asm volatile("s_waitcnt lgkmcnt(8)" ::: "memory");
        __builtin_amdgcn_s_barrier();
        asm volatile("s_waitcnt lgkmcnt(0)" ::: "memory");
        __builtin_amdgcn_s_setprio(1);
        acc[0][0] = MFMA(a01, b01, MFMA(a00, b00, acc[0][0]));
        acc[1][0] = MFMA(a11, b01, MFMA(a10, b00, acc[1][0]));
        acc[2][0] = MFMA(a21, b01, MFMA(a20, b00, acc[2][0]));
        acc[3][0] = MFMA(a31, b01, MFMA(a30, b00, acc[3][0]));
        acc[0][1] = MFMA(a01, b11, MFMA(a00, b10, acc[0][1]));
        acc[1][1] = MFMA(a11, b11, MFMA(a10, b10, acc[1][1]));
        acc[2][1] = MFMA(a21, b11, MFMA(a20, b10, acc[2][1]));
        acc[3][1] = MFMA(a31, b11, MFMA(a30, b10, acc[3][1]));
        __builtin_amdgcn_s_setprio(0);
        __builtin_amdgcn_s_barrier();

        // ---- p2: Q(m0-3, n2-3), 4 reads, stage A(t+1)h1 ----
        b20 = LDF(Bb, rb + 32, coe0); b21 = LDF(Bb, rb + 32, coe1);
        b30 = LDF(Bb, rb + 48, coe0); b31 = LDF(Bb, rb + 48, coe1);
        stage_half(A, &smem[1][0][0], tid, tileM, K, k1, 1);
        __builtin_amdgcn_s_barrier();
        asm volatile("s_waitcnt lgkmcnt(0)" ::: "memory");
        __builtin_amdgcn_s_setprio(1);
        acc[0][2] = MFMA(a01, b21, MFMA(a00, b20, acc[0][2]));
        acc[1][2] = MFMA(a11, b21, MFMA(a10, b20, acc[1][2]));
        acc[2][2] = MFMA(a21, b21, MFMA(a20, b20, acc[2][2]));
        acc[3][2] = MFMA(a31, b21, MFMA(a30, b20, acc[3][2]));
        acc[0][3] = MFMA(a01, b31, MFMA(a00, b30, acc[0][3]));
        acc[1][3] = MFMA(a11, b31, MFMA(a10, b30, acc[1][3]));
        acc[2][3] = MFMA(a21, b31, MFMA(a20, b30, acc[2][3]));
        acc[3][3] = MFMA(a31, b31, MFMA(a30, b30, acc[3][3]));
        __builtin_amdgcn_s_setprio(0);
        __builtin_amdgcn_s_barrier();

        // ---- p3: Q(m4-7, n2-3), 8 reads, stage B(t+2)h0 ----
        c00 = LDF(Ab, ra + 64, coe0);  c01 = LDF(Ab, ra + 64, coe1);
        c10 = LDF(Ab, ra + 80, coe0);  c11 = LDF(Ab, ra + 80, coe1);
        c20 = LDF(Ab, ra + 96, coe0);  c21 = LDF(Ab, ra + 96, coe1);
        c30 = LDF(Ab, ra + 112, coe0); c31 = LDF(Ab, ra + 112, coe1);
        if (pf2) stage_half(B, &smem[0][1][0], tid, tileN, K, k2, 0);
        __builtin_amdgcn_s_barrier();
        asm volatile("s_waitcnt lgkmcnt(0)" ::: "memory");
        __builtin_amdgcn_s_setprio(1);
        acc[4][2] = MFMA(c01, b21, MFMA(c00, b20, acc[4][2]));
        acc[5][2] = MFMA(c11, b21, MFMA(c10, b20, acc[5][2]));
        acc[6][2] = MFMA(c21, b21, MFMA(c20, b20, acc[6][2]));
        acc[7][2] = MFMA(c31, b21, MFMA(c30, b20, acc[7][2]));
        acc[4][3] = MFMA(c01, b31, MFMA(c00, b30, acc[4][3]));
        acc[5][3] = MFMA(c11, b31, MFMA(c10, b30, acc[5][3]));
        acc[6][3] = MFMA(c21, b31, MFMA(c20, b30, acc[6][3]));
        acc[7][3] = MFMA(c31, b31, MFMA(c30, b30, acc[7][3]));
        __builtin_amdgcn_s_setprio(0);
        __builtin_amdgcn_s_barrier();

        // ---- p4: Q(m4-7, n0-1), 0 reads, stage B(t+2)h1, vmcnt ----
        if (pf2) stage_half(B, &smem[0][1][0], tid, tileN, K, k2, 1);
        if (pf2)
            asm volatile("s_waitcnt vmcnt(4)" ::: "memory");
        else
            asm volatile("s_waitcnt vmcnt(0)" ::: "memory");
        __builtin_amdgcn_s_barrier();
        __builtin_amdgcn_s_setprio(1);
        acc[4][0] = MFMA(c01, b01, MFMA(c00, b00, acc[4][0]));
        acc[5][0] = MFMA(c11, b01, MFMA(c10, b00, acc[5][0]));
        acc[6][0] = MFMA(c21, b01, MFMA(c20, b00, acc[6][0]));
        acc[7][0] = MFMA(c31, b01, MFMA(c30, b00, acc[7][0]));
        acc[4][1] = MFMA(c01, b11, MFMA(c00, b10, acc[4][1]));
        acc[5][1] = MFMA(c11, b11, MFMA(c10, b10, acc[5][1]));
        acc[6][1] = MFMA(c21, b11, MFMA(c20, b10, acc[6][1]));
        acc[7][1] = MFMA(c31, b11, MFMA(c30, b10, acc[7][1]));
        __builtin_amdgcn_s_setprio(0);
        __builtin_amdgcn_s_barrier();

        // ================== K-tile t+1 (buf1) ==================
        Ab = &smem[1][0][0];
        Bb = &smem[1][1][0];

        // ---- p5: Q(m0-3, n0-1), 12 reads, stage A(t+2)h0 ----
        a00 = LDF(Ab, ra + 0, coe0);  a01 = LDF(Ab, ra + 0, coe1);
        a10 = LDF(Ab, ra + 16, coe0); a11 = LDF(Ab, ra + 16, coe1);
        a20 = LDF(Ab, ra + 32, coe0); a21 = LDF(Ab, ra + 32, coe1);
        a30 = LDF(Ab, ra + 48, coe0); a31 = LDF(Ab, ra + 48, coe1);
        b00 = LDF(Bb, rb + 0, coe0);  b01 = LDF(Bb, rb + 0, coe1);
        b10 = LDF(Bb, rb + 16, coe0); b11 = LDF(Bb, rb + 16, coe1);
        if (pf2) stage_half(A, &smem[0][0][0], tid, tileM, K, k2, 0);
        asm volatile("s_waitcnt lgkmcnt(8)" ::: "memory");
        __builtin_amdgcn_s_barrier();
        asm volatile("s_waitcnt lgkmcnt(0)" ::: "memory");
        __builtin_amdgcn_s_setprio(1);
        acc[0][0] = MFMA(a01, b01, MFMA(a00, b00, acc[0][0]));
        acc[1][0] = MFMA(a11, b01, MFMA(a10, b00, acc[1][0]));
        acc[2][0] = MFMA(a21, b01, MFMA(a20, b00, acc[2][0]));
        acc[3][0] = MFMA(a31, b01, MFMA(a30, b00, acc[3][0]));
        acc[0][1] = MFMA(a01, b11, MFMA(a00, b10, acc[0][1]));
        acc[1][1] = MFMA(a11, b11, MFMA(a10, b10, acc[1][1]));
        acc[2][1] = MFMA(a21, b11, MFMA(a20, b10, acc[2][1]));
        acc[3][1] = MFMA(a31, b11, MFMA(a30, b10, acc[3][1]));
        __builtin_amdgcn_s_setprio(0);
        __builtin_amdgcn_s_barrier();

        // ---- p6: Q(m0-3, n2-3), 4 reads, stage A(t+2)h1 ----
        b20 = LDF(Bb, rb + 32, coe0); b21 = LDF(Bb, rb + 32, coe1);
        b30 = LDF(Bb, rb + 48, coe0); b31 = LDF(Bb, rb + 48, coe1);
        if (pf2) stage_half(A, &smem[0][0][0], tid, tileM, K, k2, 1);
        __builtin_amdgcn_s_barrier();
        asm volatile("s_waitcnt lgkmcnt(0)" ::: "memory");
        __builtin_amdgcn_s_setprio(1);
        acc[0][2] = MFMA(a01, b21, MFMA(a00, b20, acc[0][2]));
        acc[1][2] = MFMA(a11, b21, MFMA(a10, b20, acc[1][2]));
        acc[2][2] = MFMA(a21, b21, MFMA(a20, b20, acc[2][2]));
        acc[3][2] = MFMA(a31, b21, MFMA(a30, b20, acc[3][2]));
        acc[0][3] = MFMA(a01, b31, MFMA(a00, b30, acc[0][3]));
        acc[1][3] = MFMA(a11, b31, MFMA(a10, b30, acc[1][3]));
        acc[2][3] = MFMA(a21, b31, MFMA(a20, b30, acc[2][3]));
        acc[3][3] = MFMA(a31, b31, MFMA(a30, b30, acc[3][3]));
        __builtin_amdgcn_s_setprio(0);
        __builtin_amdgcn_s_barrier();

        // ---- p7: Q(m4-7, n2-3), 8 reads, stage B(t+3)h0 ----
        c00 = LDF(Ab, ra + 64, coe0);  c01 = LDF(Ab, ra + 64, coe1);
        c10 = LDF(Ab, ra + 80, coe0);  c11 = LDF(Ab, ra + 80, coe1);
        c20 = LDF(Ab, ra + 96, coe0);  c21 = LDF(Ab, ra + 96, coe1);
        c30 = LDF(Ab, ra + 112, coe0); c31 = LDF(Ab, ra + 112, coe1);
        if (t + 3 < NT) stage_half(B, &smem[1][1][0], tid, tileN, K, k3, 0);
        __builtin_amdgcn_s_barrier();
        asm volatile("s_waitcnt lgkmcnt(0)" ::: "memory");
        __builtin_amdgcn_s_setprio(1);
        acc[4][2] = MFMA(c01, b21, MFMA(c00, b20, acc[4][2]));
        acc[5][2] = MFMA(c11, b21, MFMA(c10, b20, acc[5][2]));
        acc[6][2] = MFMA(c21, b21, MFMA(c20, b20, acc[6][2]));
        acc[7][2] = MFMA(c31, b21, MFMA(c30, b20, acc[7][2]));
        acc[4][3] = MFMA(c01, b31, MFMA(c00, b30, acc[4][3]));
        acc[5][3] = MFMA(c11, b31, MFMA(c10, b30, acc[5][3]));
        acc[6][3] = MFMA(c21, b31, MFMA(c20, b30, acc[6][3]));
        acc[7][3] = MFMA(c31, b31, MFMA(c30, b30, acc[7][3]));
        __builtin_amdgcn_s_setprio(0);
        __builtin_amdgcn_s_barrier();

        // ---- p8: Q(m4-7, n0-1), 0 reads, stage B(t+3)h1, vmcnt ----
        if (t + 3 < NT) stage_half(B, &smem[1][1][0], tid, tileN, K, k3, 1);
        if (t + 3 < NT)
            asm volatile("s_waitcnt vmcnt(4)" ::: "memory");
        else if (pf2)
            asm volatile("s_waitcnt vmcnt(0)" ::: "memory");
        __builtin_amdgcn_s_barrier();
        __builtin_amdgcn_s_setprio(1);
        acc[4][0] = MFMA(c01, b01, MFMA(c00, b00, acc[4][0]));
        acc[5][0] = MFMA(c11, b01, MFMA(c10, b00, acc[5][0]));
        acc[6][0] = MFMA(c21, b01, MFMA(c20, b00, acc[6][0]));
        acc[7][0] = MFMA(c31, b01, MFMA(c30, b00, acc[7][0]));
        acc[4][1] = MFMA(c01, b11, MFMA(c00, b10, acc[4][1]));
        acc[5][1] = MFMA(c11, b11, MFMA(c10, b10, acc[5][1]));
        acc[6][1] = MFMA(c21, b11, MFMA(c20, b10, acc[6][1]));
        acc[7][1] = MFMA(c31, b11, MFMA(c30, b10, acc[7][1]));
        __builtin_amdgcn_s_setprio(0);
        __builtin_amdgcn_s_barrier();
    }

    // ---- epilogue: C/D layout col = lane&15, row = (lane>>4)*4 + reg ----
    const int c0 = tileN + wc * 64 + l15;
    const int r0 = tileM + wr * 128 + lh * 4;
#pragma unroll
    for (int m = 0; m < 8; ++m)
#pragma unroll
        for (int n = 0; n < 4; ++n)
#pragma unroll
            for (int r = 0; r < 4; ++r)
                C[(size_t)(r0 + m * 16 + r) * N + (c0 + n * 16)] =
                    acc[m][n][r];
}

// ---------------------------------------------------------------------------
extern "C" void kernel_launch(void* const* d_in, const int* in_sizes, int n_in,
                              void* d_out, int out_size, void* d_ws,
                              size_t ws_size, hipStream_t stream) {
    const float* x = (const float*)d_in[0];  // [B,S,IN]  f32
    const float* w = (const float*)d_in[1];  // [OUT,IN]  f32
    float* out = (float*)d_out;              // [B,S,OUT] f32

    const long long MK = (long long)in_sizes[0];
    const long long NK = (long long)in_sizes[1];
    const long long MN = (long long)out_size;
    const long long K =
        (long long)(sqrt((double)MK * (double)NK / (double)MN) + 0.5);
    const long long M = MK / K;  // 16384
    const long long N = NK / K;  // 2048

    unsigned short* qx = (unsigned short*)d_ws;  // M*K bf16
    unsigned short* qw = qx + MK;                // N*K bf16

    quant_fake_int8_kernel<<<(int)(MK / 1024), 256, 0, stream>>>(x, qx, MK);
    quant_fake_int8_kernel<<<(int)(NK / 1024), 256, 0, stream>>>(w, qw, NK);

    dim3 grid((int)((M / BM) * (N / BN)));  // 64 * 8 = 512
    gemm_bf16_tmpl<<<grid, 512, 0, stream>>>(qx, qw, out, (int)M, (int)N,
                                             (int)K);
}